// Round 4
// baseline (2389.175 us; speedup 1.0000x reference)
//
#include <hip/hip_runtime.h>
#include <hip/hip_bf16.h>
#include <cstdint>

typedef unsigned short u16;
typedef __attribute__((ext_vector_type(8))) short short8;
typedef __attribute__((ext_vector_type(4))) float floatx4;
typedef __attribute__((ext_vector_type(4))) int intx4;

#define PA_TOTAL 13696   // sum of per-level pixel counts, each padded to 128
#define CCH 256
#define KTOT 2304        // 9 taps * 256 ic

struct Tables {
  int H[5], W[5], P[5], base[5], tile0[5];
  int lb[5], bb[5], cb[5];   // d_out offsets: logits, bbox, centerness per level
};
struct FeatPtrs { const float* f[5]; };
struct ConvArgs {
  const u16* X[2];      // per-tower input (raw prev-conv out when FUSE, bufIn at s=0)
  const u16* Wt[2];     // per-tower weight matrices for this stage
  u16* outB[2];         // per-tower conv output (bf16 NHWC, RAW - GN applied downstream)
  float* stats;         // OUT stats  [tower][(b*5+lvl)*32+g][2], tower stride 640 floats
  const float* statsIn; // IN stats (previous stage)
  const float* gG[2];   // previous stage's gamma per tower
  const float* gB[2];   // previous stage's beta  per tower
  float* dout;
  const float* biasCls; const float* biasCtr; const float* biasBox; const float* scales;
};

__device__ __forceinline__ u16 f2bf(float f) {
  union { float f; unsigned u; } v; v.f = f;
  unsigned r = v.u + 0x7fffu + ((v.u >> 16) & 1u);   // RNE
  return (u16)(r >> 16);
}
__device__ __forceinline__ float bf2f(u16 h) {
  union { unsigned u; float f; } v; v.u = ((unsigned)h) << 16;
  return v.f;
}

// GN+ReLU affine transform of one staged chunk (8 bf16): y = max(0, v*A + C)
__device__ __forceinline__ intx4 gn_relu(intx4 r, const float* A, const float* C) {
  union { intx4 i; short8 s; } u; u.i = r;
  short8 o;
#pragma unroll
  for (int j = 0; j < 8; ++j) {
    float v = bf2f((u16)u.s[j]);
    float y = fmaxf(fmaf(v, A[j], C[j]), 0.f);
    o[j] = (short)f2bf(y);
  }
  union { short8 s; intx4 i; } w; w.s = o;
  return w.i;
}

// per-icb GN coefficients for this thread's 8-channel chunk (one group)
__device__ __forceinline__ void gn_coeff(const float* stT, const float* G0, const float* B0,
                                         int icb, int qsw, float invcnt,
                                         float* A, float* C) {
  const float* st = stT + (size_t)(icb * 8 + (qsw >> 3)) * 2;
  float mean = st[0] * invcnt;
  float var  = fmaxf(st[1] * invcnt - mean * mean, 0.f);
  float inv  = rsqrtf(var + 1e-5f);
  const float* G = G0 + icb * 64 + qsw;
  const float* B = B0 + icb * 64 + qsw;
#pragma unroll
  for (int j = 0; j < 8; ++j) { float g = G[j] * inv; A[j] = g; C[j] = B[j] - mean * g; }
}

// ---- weight reorder, coalesced: one block per row; read row [256 ic][9 tap] f32
// contiguously into LDS, write [9 tap][256 ic] bf16 contiguously.
__global__ void reorder_rows(const float* __restrict__ src, u16* __restrict__ out) {
  __shared__ float row[KTOT];
  const int r = blockIdx.x;
  const float* s = src + (size_t)r * KTOT;
  u16* o = out + (size_t)r * KTOT;
#pragma unroll
  for (int j = 0; j < 9; ++j) row[threadIdx.x + j * 256] = s[threadIdx.x + j * 256];
  __syncthreads();
#pragma unroll
  for (int j = 0; j < 9; ++j) {
    int k = threadIdx.x + j * 256;
    o[k] = f2bf(row[(k & 255) * 9 + (k >> 8)]);
  }
}

// cls_pred (20 rows) + ctr_pred (1 row) combined into 21-row weight matrix
__global__ void reorder_pred_cls(const float* __restrict__ cls_w, const float* __restrict__ ctr_w,
                                 u16* __restrict__ out) {
  __shared__ float row[KTOT];
  const int r = blockIdx.x;   // 0..20
  const float* s = (r < 20) ? (cls_w + (size_t)r * KTOT) : ctr_w;
  u16* o = out + (size_t)r * KTOT;
#pragma unroll
  for (int j = 0; j < 9; ++j) row[threadIdx.x + j * 256] = s[threadIdx.x + j * 256];
  __syncthreads();
#pragma unroll
  for (int j = 0; j < 9; ++j) {
    int k = threadIdx.x + j * 256;
    o[k] = f2bf(row[(k & 255) * 9 + (k >> 8)]);
  }
}

// ---- inputs NCHW f32 -> NHWC bf16, 32x32 LDS transpose (coalesced both sides)
// grid: (PA_TOTAL/32, 8, 2)  block 256
__global__ void convert_inputs(FeatPtrs fp, u16* __restrict__ out, Tables tb) {
  __shared__ float tile[32][33];
  const int pt = blockIdx.x, c32 = blockIdx.y, b = blockIdx.z;
  const int p0 = pt * 32;
  int lvl = 0;
#pragma unroll
  for (int i = 1; i < 5; ++i) if (p0 >= tb.base[i]) lvl = i;
  const int P = tb.P[lvl];
  const int pl0 = p0 - tb.base[lvl];
  const int r = threadIdx.x >> 5, col = threadIdx.x & 31;
  const float* src = fp.f[lvl] + ((size_t)b * CCH + c32 * 32) * P;
#pragma unroll
  for (int i = 0; i < 4; ++i) {
    int crow = r + i * 8;
    int pl = pl0 + col;
    tile[crow][col] = (pl < P) ? src[(size_t)crow * P + pl] : 0.f;
  }
  __syncthreads();
#pragma unroll
  for (int i = 0; i < 4; ++i) {
    int px = r + i * 8;
    out[((size_t)b * PA_TOTAL + p0 + px) * CCH + c32 * 32 + col] = f2bf(tile[col][px]);
  }
}

// ---- implicit-GEMM conv3x3 SAME, bf16 MFMA 16x16x32, BK=64, 128-px tiles:
// the proven R2 structure (119us/dispatch) - LDS staging + register prefetch -
// kept bit-identical. THIS ROUND: GroupNorm+ReLU FUSED INTO STAGING. The
// separate gn_norm pass (4 dispatches, 56MB traffic each, ~100us total) is
// deleted: conv reads the PREVIOUS conv's RAW bf16 output and applies
// y = max(0, v*A + C) (A = gamma*rsqrt(var+eps), C = beta - mean*A, from the
// completed previous-stage stats) to the prefetched registers in the
// POST-MFMA SLACK (not the barrier-to-barrier stage window). Coefficients
// (16 VGPRs) reload once per icb. Halo-invalid chunks re-zeroed after the
// transform (GN of 0 is nonzero!). Requires ping-ponged conv-out buffer pairs
// (read s-1's pair, write the other) to avoid RAW races across tiles.
// launch_bounds(256,4) caps VGPR at 128 to hold 4 blocks/CU residency.
// MODE 0: 128x128 tile, tower stage -> raw bf16 NHWC + GN stats. grid (107,2,4).
// MODE 1: 32x128 tile (21/4 real oc rows), pred convs -> d_out NCHW. grid (108,2,2).
template <int MODE, int FUSE>
__global__ __launch_bounds__(256, 4) void conv_mfma(ConvArgs a, Tables tb) {
  constexpr int NI = (MODE == 0) ? 4 : 1;     // A-frag rows per wave
  const int L = blockIdx.x + (MODE == 0 ? 107 : 108) * (blockIdx.y + 2 * blockIdx.z);
  const int xcd = L & 7, slot = L >> 3;
  int tower, mt, b, t;
  if (MODE == 0) {
    tower = xcd >> 2; mt = (xcd >> 1) & 1; b = xcd & 1; t = slot;
  } else {
    tower = xcd >> 2; mt = 0; b = (xcd >> 1) & 1; t = slot * 2 + (xcd & 1);
    if (t >= 107) return;
  }
  int lvl = 0;
#pragma unroll
  for (int i = 1; i < 5; ++i) if (t >= tb.tile0[i]) lvl = i;
  const int H = tb.H[lvl], W = tb.W[lvl], P = tb.P[lvl], base = tb.base[lvl];
  const int n0 = (t - tb.tile0[lvl]) * 128;

  const int tid = threadIdx.x;
  const int lane = tid & 63, wv = tid >> 6;
  const int wm = wv >> 1, wn = wv & 1;

  __shared__ u16 ldsX[128 * 64];                       // [px][64 ic] swizzled, 16KB
  __shared__ u16 ldsW[(MODE == 0 ? 128 : 32) * 64];    // [oc][64 k] swizzled

  const u16* X = a.X[tower];
  const u16* Wt = a.Wt[tower];

  // staging geometry: chunk ci = (t4*4+wv)*64 + lane -> row=ci>>3, col=lane&7;
  // slot (row,col) holds k-chunk q' = col ^ (row&7), a per-thread constant.
  const int qsw = (((lane & 7) ^ (lane >> 3))) * 8;   // u16 offset of fetched chunk
  int prow[4];
  unsigned mask9[4];
  int xdst[4];                       // per-lane LDS byte dests
#pragma unroll
  for (int t4 = 0; t4 < 4; ++t4) {
    int row = (t4 * 4 + wv) * 8 + (lane >> 3);
    prow[t4] = n0 + row;
    int rr = prow[t4] / W, cc = prow[t4] - rr * W;
    unsigned m = 0;
#pragma unroll
    for (int tap = 0; tap < 9; ++tap) {
      const int dh = tap / 3 - 1, dw = tap % 3 - 1;
      bool v = ((unsigned)(rr + dh) < (unsigned)H) & ((unsigned)(cc + dw) < (unsigned)W);
      m |= ((unsigned)v) << tap;
    }
    mask9[t4] = m;
    xdst[t4] = (t4 * 4 + wv) * 1024 + lane * 16;
  }
  const u16* wsrc[NI];
  int wdst[NI];
#pragma unroll
  for (int e = 0; e < NI; ++e) {
    int wrow = (MODE == 0) ? ((e * 4 + wv) * 8 + (lane >> 3)) : (wv * 8 + (lane >> 3));
    wsrc[e] = Wt + (size_t)(mt * 128 + wrow) * KTOT + qsw;
    wdst[e] = (MODE == 0) ? xdst[e] : (wv * 1024 + lane * 16);
  }
  const u16* Xbp = X + ((size_t)b * PA_TOTAL + base) * CCH;

  // fragment LDS offsets (u16), reader swizzle col = kq ^ (row&7)
  const int arow = lane & 15, rsw = lane & 7, kq0 = lane >> 4;
  int aoff[2][NI], boff[2][4];
#pragma unroll
  for (int h = 0; h < 2; ++h) {
    int csw = (((h * 4 + kq0) ^ rsw)) * 8;
#pragma unroll
    for (int i = 0; i < NI; ++i) {
      int rowb = (MODE == 0) ? (wm * 64 + i * 16) : (wm * 16);
      aoff[h][i] = (rowb + arow) * 64 + csw;
    }
#pragma unroll
    for (int i = 0; i < 4; ++i) boff[h][i] = (wn * 64 + i * 16 + arow) * 64 + csw;
  }

  floatx4 acc[NI][4];
#pragma unroll
  for (int i = 0; i < NI; ++i)
#pragma unroll
    for (int j = 0; j < 4; ++j) acc[i][j] = (floatx4)0.f;

  // GN fusion state: per-thread chunk coefficients (one 8-ch group per icb)
  float A8[8], C8[8];
  const float invcnt = FUSE ? (1.f / (8.f * (float)P)) : 0.f;
  const float* stT = FUSE ? (a.statsIn + tower * 640 + (size_t)((b * 5 + lvl) * 32) * 2) : nullptr;
  const float* gGt = FUSE ? a.gG[tower] : nullptr;
  const float* gBt = FUSE ? a.gB[tower] : nullptr;

  const intx4 zreg = {0, 0, 0, 0};
  intx4 xr[4], wr[NI];
  // prologue: issue loads for step (icb=0, tap=0); dpos = -W-1
  {
    const int dpos0 = -W - 1;
#pragma unroll
    for (int t4 = 0; t4 < 4; ++t4)
      xr[t4] = (mask9[t4] & 1)
          ? *(const intx4*)(Xbp + (size_t)(prow[t4] + dpos0) * CCH + qsw) : zreg;
#pragma unroll
    for (int e = 0; e < NI; ++e) wr[e] = *(const intx4*)(wsrc[e]);
    if (FUSE) {
      gn_coeff(stT, gGt, gBt, 0, qsw, invcnt, A8, C8);
#pragma unroll
      for (int t4 = 0; t4 < 4; ++t4) {
        intx4 tr = gn_relu(xr[t4], A8, C8);
        xr[t4] = (mask9[t4] & 1u) ? tr : zreg;
      }
    }
  }

  // K-loop: icb outer, taps inner (unrolled). Per step: __syncthreads (prev
  // readers done; vmcnt(0) waits step-old loads) -> ds_write staged (already
  // GN-transformed) regs -> issue next step's RAW loads -> lgkm-barrier ->
  // MFMA -> [FUSE] transform next step's regs in the post-MFMA slack.
#pragma unroll 1
  for (int icb = 0; icb < 4; ++icb) {
#pragma unroll
    for (int tap = 0; tap < 9; ++tap) {
      __syncthreads();
#pragma unroll
      for (int t4 = 0; t4 < 4; ++t4) *(intx4*)((char*)ldsX + xdst[t4]) = xr[t4];
#pragma unroll
      for (int e = 0; e < NI; ++e) *(intx4*)((char*)ldsW + wdst[e]) = wr[e];
      if (!(icb == 3 && tap == 8)) {
        const int ntap = (tap == 8) ? 0 : tap + 1;
        const int nicb = (tap == 8) ? icb + 1 : icb;
        const int ndh = ntap / 3;
        const int ndpos = (ndh - 1) * W + (ntap - 3 * ndh - 1);
        const int nko = ntap * 256 + nicb * 64;
#pragma unroll
        for (int t4 = 0; t4 < 4; ++t4)
          xr[t4] = ((mask9[t4] >> ntap) & 1)
              ? *(const intx4*)(Xbp + (size_t)(prow[t4] + ndpos) * CCH + qsw + nicb * 64) : zreg;
#pragma unroll
        for (int e = 0; e < NI; ++e) wr[e] = *(const intx4*)(wsrc[e] + nko);
      }
      // pre-MFMA barrier: ds_writes visible (lgkm only; fresh loads in flight)
      asm volatile("s_waitcnt lgkmcnt(0)\n\ts_barrier" ::: "memory");
#pragma unroll
      for (int h = 0; h < 2; ++h) {
        short8 af[NI], bv[4];
#pragma unroll
        for (int i = 0; i < NI; ++i) af[i] = *(const short8*)(ldsW + aoff[h][i]);
#pragma unroll
        for (int j = 0; j < 4; ++j) bv[j] = *(const short8*)(ldsX + boff[h][j]);
#pragma unroll
        for (int i = 0; i < NI; ++i)
#pragma unroll
          for (int j = 0; j < 4; ++j)
            acc[i][j] = __builtin_amdgcn_mfma_f32_16x16x32_bf16(af[i], bv[j], acc[i][j], 0, 0, 0);
      }
      // post-MFMA slack: GN+ReLU the freshly prefetched regs for the NEXT step
      if (FUSE) {
        if (!(icb == 3 && tap == 8)) {
          const int ntap2 = (tap == 8) ? 0 : tap + 1;
          if (tap == 8)
            gn_coeff(stT, gGt, gBt, icb + 1, qsw, invcnt, A8, C8);
#pragma unroll
          for (int t4 = 0; t4 < 4; ++t4) {
            intx4 tr = gn_relu(xr[t4], A8, C8);
            xr[t4] = ((mask9[t4] >> ntap2) & 1u) ? tr : zreg;
          }
        }
      }
    }
  }

  // epilogue; D[m=(lane>>4)*4+r][n=lane&15]
  const int quad = lane >> 4, col = lane & 15;
  if (MODE == 0) {
    u16* convB = a.outB[tower];
    float s[4] = {0.f, 0.f, 0.f, 0.f}, ss[4] = {0.f, 0.f, 0.f, 0.f};
#pragma unroll
    for (int j = 0; j < 4; ++j) {
      int pl = n0 + wn * 64 + j * 16 + col;
      bool valid = pl < P;
      u16* dst = convB + ((size_t)b * PA_TOTAL + base + pl) * CCH + mt * 128 + wm * 64 + quad * 4;
#pragma unroll
      for (int i = 0; i < 4; ++i) {
        ushort4 hv;
#pragma unroll
        for (int r = 0; r < 4; ++r) {
          u16 hh = f2bf(acc[i][j][r]);
          ((u16*)&hv)[r] = hh;
          float vr = bf2f(hh);                    // accumulate ROUNDED value -> GN self-consistent
          if (valid) { s[i] += vr; ss[i] += vr * vr; }
        }
        if (valid) *(ushort4*)(dst + i * 16) = hv;
      }
    }
#pragma unroll
    for (int i = 0; i < 4; ++i) {
#pragma unroll
      for (int off = 16; off >= 1; off >>= 1) {
        s[i] += __shfl_down(s[i], off, 64);
        ss[i] += __shfl_down(ss[i], off, 64);
      }
    }
    if ((lane & 31) == 0) {
      int half = lane >> 5;
#pragma unroll
      for (int i = 0; i < 4; ++i) {
        float* st = a.stats + tower * 640 +
                    ((size_t)((b * 5 + lvl) * 32 + mt * 16 + wm * 8 + i * 2 + half)) * 2;
        atomicAdd(st, s[i]);
        atomicAdd(st + 1, ss[i]);
      }
    }
  } else {
    float* dout = a.dout;
    if (tower == 0) {
#pragma unroll
      for (int j = 0; j < 4; ++j) {
        int pl = n0 + wn * 64 + j * 16 + col;
        if (pl >= P) continue;
        int ocb = wm * 16 + quad * 4;
#pragma unroll
        for (int r = 0; r < 4; ++r) {
          int oc = ocb + r;
          float v = acc[0][j][r];
          if (oc < 20)       dout[tb.lb[lvl] + ((size_t)b * 20 + oc) * P + pl] = v + a.biasCls[oc];
          else if (oc == 20) dout[tb.cb[lvl] + (size_t)b * P + pl] = v + a.biasCtr[0];
        }
      }
    } else {
      float sc = a.scales[lvl];
#pragma unroll
      for (int j = 0; j < 4; ++j) {
        int pl = n0 + wn * 64 + j * 16 + col;
        if (pl >= P) continue;
        int ocb = wm * 16 + quad * 4;
#pragma unroll
        for (int r = 0; r < 4; ++r) {
          int oc = ocb + r;
          if (oc < 4)
            dout[tb.bb[lvl] + ((size_t)b * 4 + oc) * P + pl] = expf((acc[0][j][r] + a.biasBox[oc]) * sc);
        }
      }
    }
  }
}

extern "C" void kernel_launch(void* const* d_in, const int* in_sizes, int n_in,
                              void* d_out, int out_size, void* d_ws, size_t ws_size,
                              hipStream_t stream) {
  const float* feat[5];
  for (int i = 0; i < 5; ++i) feat[i] = (const float*)d_in[i];
  const float* cls_tw_w  = (const float*)d_in[5];
  const float* cls_tw_g  = (const float*)d_in[6];
  const float* cls_tw_b  = (const float*)d_in[7];
  const float* box_tw_w  = (const float*)d_in[8];
  const float* box_tw_g  = (const float*)d_in[9];
  const float* box_tw_b  = (const float*)d_in[10];
  const float* cls_pred_w = (const float*)d_in[11];
  const float* cls_pred_b = (const float*)d_in[12];
  const float* box_pred_w = (const float*)d_in[13];
  const float* box_pred_b = (const float*)d_in[14];
  const float* ctr_pred_w = (const float*)d_in[15];
  const float* ctr_pred_b = (const float*)d_in[16];
  const float* scales     = (const float*)d_in[17];
  float* out = (float*)d_out;

  char* ws = (char*)d_ws;
  float* statsA = (float*)(ws + 512);                // 5120 B
  u16*   WrCls  = (u16*)(ws + 8192);                 // 1024 x 2304 bf16
  u16*   WrBox  = (u16*)(ws + 8192 + 4718592);
  u16*   WrPCls = (u16*)(ws + 9445376);              // 32 x 2304 bf16 (21 used)
  u16*   WrPBox = (u16*)(ws + 9445376 + 147456);     // 32 x 2304 bf16 (4 used)
  float* statsB = (float*)(ws + 9445376 + 2 * 147456);  // 5120 B, ends < 10625024
  u16*   bufIn  = (u16*)(ws + 10625024);
  // ping-pong RAW conv-out pairs (GN applied by the consumer's staging)
  u16*   bufB0  = (u16*)(ws + 10625024 + 1 * (size_t)14024704);
  u16*   bufB1  = (u16*)(ws + 10625024 + 2 * (size_t)14024704);
  u16*   bufA0  = (u16*)(ws + 10625024 + 3 * (size_t)14024704);
  u16*   bufA1  = (u16*)(ws + 10625024 + 4 * (size_t)14024704);

  Tables tb = { {100,50,25,13,7}, {100,50,25,13,7}, {10000,2500,625,169,49},
                {0,10112,12672,13312,13568}, {0,79,99,104,106},
                {0,400000,500000,525000,531760},
                {533720,613720,633720,638720,640072},
                {640464,660464,665464,666714,667052} };

  hipMemsetAsync(WrPCls, 0, 147456, stream);
  hipMemsetAsync(WrPBox, 0, 147456, stream);

  reorder_rows<<<1024, 256, 0, stream>>>(cls_tw_w, WrCls);
  reorder_rows<<<1024, 256, 0, stream>>>(box_tw_w, WrBox);
  reorder_pred_cls<<<21, 256, 0, stream>>>(cls_pred_w, ctr_pred_w, WrPCls);
  reorder_rows<<<4, 256, 0, stream>>>(box_pred_w, WrPBox);

  FeatPtrs fp = {{feat[0], feat[1], feat[2], feat[3], feat[4]}};
  convert_inputs<<<dim3(PA_TOTAL / 32, 8, 2), 256, 0, stream>>>(fp, bufIn, tb);

  ConvArgs a;
  a.dout = out;
  a.biasCls = cls_pred_b; a.biasCtr = ctr_pred_b; a.biasBox = box_pred_b; a.scales = scales;

  // stage s: out pair = (s even ? A : B); reads (s==0 ? bufIn : other pair)
  for (int s = 0; s < 4; ++s) {
    a.X[0] = (s == 0) ? bufIn : ((s & 1) ? bufA0 : bufB0);
    a.X[1] = (s == 0) ? bufIn : ((s & 1) ? bufA1 : bufB1);
    a.outB[0] = (s & 1) ? bufB0 : bufA0;
    a.outB[1] = (s & 1) ? bufB1 : bufA1;
    a.Wt[0] = WrCls + (size_t)s * 256 * KTOT;
    a.Wt[1] = WrBox + (size_t)s * 256 * KTOT;
    a.stats   = (s & 1) ? statsB : statsA;   // this stage's stats out
    a.statsIn = (s & 1) ? statsA : statsB;   // previous stage's stats
    int sp = (s > 0) ? (s - 1) : 0;
    a.gG[0] = cls_tw_g + sp * 256; a.gB[0] = cls_tw_b + sp * 256;
    a.gG[1] = box_tw_g + sp * 256; a.gB[1] = box_tw_b + sp * 256;
    hipMemsetAsync(a.stats, 0, 5120, stream);
    if (s == 0) conv_mfma<0, 0><<<dim3(107, 2, 4), 256, 0, stream>>>(a, tb);
    else        conv_mfma<0, 1><<<dim3(107, 2, 4), 256, 0, stream>>>(a, tb);
  }
  // pred convs: read stage-3 raw output (B pair) + stage-3 GN params
  a.X[0] = bufB0; a.X[1] = bufB1;
  a.Wt[0] = WrPCls; a.Wt[1] = WrPBox;
  a.statsIn = statsB;
  a.gG[0] = cls_tw_g + 3 * 256; a.gB[0] = cls_tw_b + 3 * 256;
  a.gG[1] = box_tw_g + 3 * 256; a.gB[1] = box_tw_b + 3 * 256;
  conv_mfma<1, 1><<<dim3(108, 2, 2), 256, 0, stream>>>(a, tb);
}

// Round 5
// 1055.035 us; speedup vs baseline: 2.2645x; 2.2645x over previous
//
#include <hip/hip_runtime.h>
#include <hip/hip_bf16.h>
#include <cstdint>

typedef unsigned short u16;
typedef __attribute__((ext_vector_type(8))) short short8;
typedef __attribute__((ext_vector_type(4))) float floatx4;
typedef __attribute__((ext_vector_type(4))) int intx4;

#define PA_TOTAL 13696   // sum of per-level pixel counts, each padded to 128
#define CCH 256
#define KTOT 2304        // 9 taps * 256 ic

struct Tables {
  int H[5], W[5], P[5], base[5], tile0[5];
  int lb[5], bb[5], cb[5];   // d_out offsets: logits, bbox, centerness per level
};
struct FeatPtrs { const float* f[5]; };
struct ConvArgs {
  const u16* X[2];      // per-tower input (raw prev-conv out when FUSE, bufIn at s=0)
  const u16* Wt[2];     // per-tower weight matrices for this stage
  u16* outB[2];         // per-tower conv output (bf16 NHWC, RAW - GN applied downstream)
  float* stats;         // OUT stats  [tower][(b*5+lvl)*32+g][2], tower stride 640 floats
  const float* statsIn; // IN stats (previous stage)
  const float* gG[2];   // previous stage's gamma per tower
  const float* gB[2];   // previous stage's beta  per tower
  float* dout;
  const float* biasCls; const float* biasCtr; const float* biasBox; const float* scales;
};

__device__ __forceinline__ u16 f2bf(float f) {
  union { float f; unsigned u; } v; v.f = f;
  unsigned r = v.u + 0x7fffu + ((v.u >> 16) & 1u);   // RNE
  return (u16)(r >> 16);
}
__device__ __forceinline__ float bf2f(u16 h) {
  union { unsigned u; float f; } v; v.u = ((unsigned)h) << 16;
  return v.f;
}

// async global->LDS: 16B per lane, dest = wave-uniform base + lane*16.
__device__ __forceinline__ void gload16(const void* g, void* l) {
  __builtin_amdgcn_global_load_lds(
      (const __attribute__((address_space(1))) void*)g,
      (__attribute__((address_space(3))) void*)l, 16, 0, 0);
}

// GN+ReLU affine transform of one staged chunk (8 bf16): y = max(0, v*A + C)
__device__ __forceinline__ intx4 gn_relu(intx4 r, const float* A, const float* C) {
  union { intx4 i; short8 s; } u; u.i = r;
  short8 o;
#pragma unroll
  for (int j = 0; j < 8; ++j) {
    float v = bf2f((u16)u.s[j]);
    float y = fmaxf(fmaf(v, A[j], C[j]), 0.f);
    o[j] = (short)f2bf(y);
  }
  union { short8 s; intx4 i; } w; w.s = o;
  return w.i;
}

// per-icb GN coefficients for this thread's 8-channel chunk (one group)
__device__ __forceinline__ void gn_coeff(const float* stT, const float* G0, const float* B0,
                                         int icb, int qsw, float invcnt,
                                         float* A, float* C) {
  const float* st = stT + (size_t)(icb * 8 + (qsw >> 3)) * 2;
  float mean = st[0] * invcnt;
  float var  = fmaxf(st[1] * invcnt - mean * mean, 0.f);
  float inv  = rsqrtf(var + 1e-5f);
  const float* G = G0 + icb * 64 + qsw;
  const float* B = B0 + icb * 64 + qsw;
#pragma unroll
  for (int j = 0; j < 8; ++j) { float g = G[j] * inv; A[j] = g; C[j] = B[j] - mean * g; }
}

// ---- weight reorder, coalesced: one block per row; read row [256 ic][9 tap] f32
// contiguously into LDS, write [9 tap][256 ic] bf16 contiguously.
__global__ void reorder_rows(const float* __restrict__ src, u16* __restrict__ out) {
  __shared__ float row[KTOT];
  const int r = blockIdx.x;
  const float* s = src + (size_t)r * KTOT;
  u16* o = out + (size_t)r * KTOT;
#pragma unroll
  for (int j = 0; j < 9; ++j) row[threadIdx.x + j * 256] = s[threadIdx.x + j * 256];
  __syncthreads();
#pragma unroll
  for (int j = 0; j < 9; ++j) {
    int k = threadIdx.x + j * 256;
    o[k] = f2bf(row[(k & 255) * 9 + (k >> 8)]);
  }
}

// cls_pred (20 rows) + ctr_pred (1 row) combined into 21-row weight matrix
__global__ void reorder_pred_cls(const float* __restrict__ cls_w, const float* __restrict__ ctr_w,
                                 u16* __restrict__ out) {
  __shared__ float row[KTOT];
  const int r = blockIdx.x;   // 0..20
  const float* s = (r < 20) ? (cls_w + (size_t)r * KTOT) : ctr_w;
  u16* o = out + (size_t)r * KTOT;
#pragma unroll
  for (int j = 0; j < 9; ++j) row[threadIdx.x + j * 256] = s[threadIdx.x + j * 256];
  __syncthreads();
#pragma unroll
  for (int j = 0; j < 9; ++j) {
    int k = threadIdx.x + j * 256;
    o[k] = f2bf(row[(k & 255) * 9 + (k >> 8)]);
  }
}

// ---- inputs NCHW f32 -> NHWC bf16, 32x32 LDS transpose (coalesced both sides)
// grid: (PA_TOTAL/32, 8, 2)  block 256
__global__ void convert_inputs(FeatPtrs fp, u16* __restrict__ out, Tables tb) {
  __shared__ float tile[32][33];
  const int pt = blockIdx.x, c32 = blockIdx.y, b = blockIdx.z;
  const int p0 = pt * 32;
  int lvl = 0;
#pragma unroll
  for (int i = 1; i < 5; ++i) if (p0 >= tb.base[i]) lvl = i;
  const int P = tb.P[lvl];
  const int pl0 = p0 - tb.base[lvl];
  const int r = threadIdx.x >> 5, col = threadIdx.x & 31;
  const float* src = fp.f[lvl] + ((size_t)b * CCH + c32 * 32) * P;
#pragma unroll
  for (int i = 0; i < 4; ++i) {
    int crow = r + i * 8;
    int pl = pl0 + col;
    tile[crow][col] = (pl < P) ? src[(size_t)crow * P + pl] : 0.f;
  }
  __syncthreads();
#pragma unroll
  for (int i = 0; i < 4; ++i) {
    int px = r + i * 8;
    out[((size_t)b * PA_TOTAL + p0 + px) * CCH + c32 * 32 + col] = f2bf(tile[col][px]);
  }
}

// ---- implicit-GEMM conv3x3 SAME, bf16 MFMA 16x16x32, BK=64, 128-px tiles:
// the proven R2 structure for X (LDS staging + register prefetch, 2 barriers
// per step). THIS ROUND (fixing R4's spill):
//  * GN+ReLU fusion KEPT (numerics validated in R4): conv reads the previous
//    conv's RAW bf16 output and applies y = max(0, v*A + C) to the prefetched
//    X registers in the post-MFMA slack. A/C (16 VGPR) reload once per icb.
//  * W staging moved to DOUBLE-BUFFERED global_load_lds (W needs no GN
//    transform; its dest is already wave-uniform-base + lane*16 with the XOR
//    swizzle pre-folded into the per-lane global source). This frees the wr[]
//    staging registers (16 VGPR) - exactly paying for A8/C8 - and removes 4
//    ds_writes/wave/step. W gloads are issued right after the top sync into
//    the buffer NOT being read this step; the next step's top __syncthreads
//    (vmcnt drain) collects them, aged ~0.8 step, L2-resident source.
//  * __launch_bounds__(256) plain - NO min-wave arg (R4's (256,4) forced an
//    impossible VGPR cap -> full spill, 2.5GB scratch traffic, 5x regression).
// LDS: ldsX 16KB + ldsW 2x16KB = 48KB -> 3 blocks/CU (grid avg 3.34).
// MODE 0: 128x128 tile, tower stage -> raw bf16 NHWC + GN stats. grid (107,2,4).
// MODE 1: 32x128 tile (21/4 real oc rows), pred convs -> d_out NCHW. grid (108,2,2).
template <int MODE, int FUSE>
__global__ __launch_bounds__(256) void conv_mfma(ConvArgs a, Tables tb) {
  constexpr int NI = (MODE == 0) ? 4 : 1;     // A-frag rows per wave
  constexpr int WROWS = (MODE == 0) ? 128 : 32;
  constexpr int WSZ = WROWS * 64;             // u16 elems per W buffer
  const int L = blockIdx.x + (MODE == 0 ? 107 : 108) * (blockIdx.y + 2 * blockIdx.z);
  const int xcd = L & 7, slot = L >> 3;
  int tower, mt, b, t;
  if (MODE == 0) {
    tower = xcd >> 2; mt = (xcd >> 1) & 1; b = xcd & 1; t = slot;
  } else {
    tower = xcd >> 2; mt = 0; b = (xcd >> 1) & 1; t = slot * 2 + (xcd & 1);
    if (t >= 107) return;
  }
  int lvl = 0;
#pragma unroll
  for (int i = 1; i < 5; ++i) if (t >= tb.tile0[i]) lvl = i;
  const int H = tb.H[lvl], W = tb.W[lvl], P = tb.P[lvl], base = tb.base[lvl];
  const int n0 = (t - tb.tile0[lvl]) * 128;

  const int tid = threadIdx.x;
  const int lane = tid & 63, wv = tid >> 6;
  const int wm = wv >> 1, wn = wv & 1;

  __shared__ u16 ldsX[128 * 64];        // [px][64 ic] swizzled, 16KB
  __shared__ u16 ldsW[2 * WSZ];         // [oc][64 k] swizzled, DOUBLE-buffered

  const u16* X = a.X[tower];
  const u16* Wt = a.Wt[tower];

  // staging geometry: chunk ci = (t4*4+wv)*64 + lane -> row=ci>>3, col=lane&7;
  // slot (row,col) holds k-chunk q' = col ^ (row&7), a per-thread constant.
  const int qsw = (((lane & 7) ^ (lane >> 3))) * 8;   // u16 offset of fetched chunk
  int prow[4];
  unsigned mask9[4];
  int xdst[4];                       // per-lane LDS byte dests (X)
#pragma unroll
  for (int t4 = 0; t4 < 4; ++t4) {
    int row = (t4 * 4 + wv) * 8 + (lane >> 3);
    prow[t4] = n0 + row;
    int rr = prow[t4] / W, cc = prow[t4] - rr * W;
    unsigned m = 0;
#pragma unroll
    for (int tap = 0; tap < 9; ++tap) {
      const int dh = tap / 3 - 1, dw = tap % 3 - 1;
      bool v = ((unsigned)(rr + dh) < (unsigned)H) & ((unsigned)(cc + dw) < (unsigned)W);
      m |= ((unsigned)v) << tap;
    }
    mask9[t4] = m;
    xdst[t4] = (t4 * 4 + wv) * 1024 + lane * 16;
  }
  // W: per-lane global sources (swizzle pre-folded via qsw) + wave-uniform LDS bases
  const u16* wsrc[NI];
  int wdst[NI];                      // wave-uniform byte base; HW adds lane*16
#pragma unroll
  for (int e = 0; e < NI; ++e) {
    int wrow = (MODE == 0) ? ((e * 4 + wv) * 8 + (lane >> 3)) : (wv * 8 + (lane >> 3));
    wsrc[e] = Wt + (size_t)(mt * 128 + wrow) * KTOT + qsw;
    wdst[e] = (MODE == 0) ? ((e * 4 + wv) * 1024) : (wv * 1024);
  }
  const u16* Xbp = X + ((size_t)b * PA_TOTAL + base) * CCH;

  // fragment LDS offsets (u16), reader swizzle col = kq ^ (row&7)
  const int arow = lane & 15, rsw = lane & 7, kq0 = lane >> 4;
  int aoff[2][NI], boff[2][4];
#pragma unroll
  for (int h = 0; h < 2; ++h) {
    int csw = (((h * 4 + kq0) ^ rsw)) * 8;
#pragma unroll
    for (int i = 0; i < NI; ++i) {
      int rowb = (MODE == 0) ? (wm * 64 + i * 16) : (wm * 16);
      aoff[h][i] = (rowb + arow) * 64 + csw;
    }
#pragma unroll
    for (int i = 0; i < 4; ++i) boff[h][i] = (wn * 64 + i * 16 + arow) * 64 + csw;
  }

  floatx4 acc[NI][4];
#pragma unroll
  for (int i = 0; i < NI; ++i)
#pragma unroll
    for (int j = 0; j < 4; ++j) acc[i][j] = (floatx4)0.f;

  // GN fusion state: per-thread chunk coefficients (one 8-ch group per icb)
  float A8[8], C8[8];
  const float invcnt = FUSE ? (1.f / (8.f * (float)P)) : 0.f;
  const float* stT = FUSE ? (a.statsIn + tower * 640 + (size_t)((b * 5 + lvl) * 32) * 2) : nullptr;
  const float* gGt = FUSE ? a.gG[tower] : nullptr;
  const float* gBt = FUSE ? a.gB[tower] : nullptr;

  const intx4 zreg = {0, 0, 0, 0};
  intx4 xr[4];
  // prologue: X regs for step 0 (+GN transform); W(0) -> ldsW buf0 via gload.
  {
    const int dpos0 = -W - 1;
#pragma unroll
    for (int t4 = 0; t4 < 4; ++t4)
      xr[t4] = (mask9[t4] & 1)
          ? *(const intx4*)(Xbp + (size_t)(prow[t4] + dpos0) * CCH + qsw) : zreg;
#pragma unroll
    for (int e = 0; e < NI; ++e) gload16(wsrc[e], (char*)ldsW + wdst[e]);
    if (FUSE) {
      gn_coeff(stT, gGt, gBt, 0, qsw, invcnt, A8, C8);
#pragma unroll
      for (int t4 = 0; t4 < 4; ++t4) {
        intx4 tr = gn_relu(xr[t4], A8, C8);
        xr[t4] = (mask9[t4] & 1u) ? tr : zreg;
      }
    }
  }

  // K-loop: icb outer, taps inner (unrolled). Per step s = icb*9+tap:
  //   __syncthreads (drains vmcnt: X(s) reg-loads + W(s) gloads, both ~1 step
  //   old; also: all waves done reading ldsX(s-1) and ldsW[(s-1)&1])
  //   -> issue W(s+1) gloads into ldsW[(s+1)&1]
  //   -> ds_write X(s) regs -> issue X(s+1) reg-loads
  //   -> lgkm-barrier (X writes visible; gloads stay in flight)
  //   -> MFMA(s) reading ldsX + ldsW[s&1]
  //   -> [FUSE] GN-transform X(s+1) regs in post-MFMA slack.
#pragma unroll 1
  for (int icb = 0; icb < 4; ++icb) {
#pragma unroll
    for (int tap = 0; tap < 9; ++tap) {
      const int s = icb * 9 + tap;
      __syncthreads();
      if (!(icb == 3 && tap == 8)) {
        const int ntap = (tap == 8) ? 0 : tap + 1;
        const int nicb = (tap == 8) ? icb + 1 : icb;
        const int nko = ntap * 256 + nicb * 64;
        char* wbufN = (char*)ldsW + ((s + 1) & 1) * (WSZ * 2);
#pragma unroll
        for (int e = 0; e < NI; ++e) gload16(wsrc[e] + nko, wbufN + wdst[e]);
      }
#pragma unroll
      for (int t4 = 0; t4 < 4; ++t4) *(intx4*)((char*)ldsX + xdst[t4]) = xr[t4];
      if (!(icb == 3 && tap == 8)) {
        const int ntap = (tap == 8) ? 0 : tap + 1;
        const int nicb = (tap == 8) ? icb + 1 : icb;
        const int ndh = ntap / 3;
        const int ndpos = (ndh - 1) * W + (ntap - 3 * ndh - 1);
#pragma unroll
        for (int t4 = 0; t4 < 4; ++t4)
          xr[t4] = ((mask9[t4] >> ntap) & 1)
              ? *(const intx4*)(Xbp + (size_t)(prow[t4] + ndpos) * CCH + qsw + nicb * 64) : zreg;
      }
      // pre-MFMA barrier: X ds_writes visible (lgkm only; gloads in flight)
      asm volatile("s_waitcnt lgkmcnt(0)\n\ts_barrier" ::: "memory");
      const u16* wc = ldsW + (s & 1) * WSZ;
#pragma unroll
      for (int h = 0; h < 2; ++h) {
        short8 af[NI], bv[4];
#pragma unroll
        for (int i = 0; i < NI; ++i) af[i] = *(const short8*)(wc + aoff[h][i]);
#pragma unroll
        for (int j = 0; j < 4; ++j) bv[j] = *(const short8*)(ldsX + boff[h][j]);
#pragma unroll
        for (int i = 0; i < NI; ++i)
#pragma unroll
          for (int j = 0; j < 4; ++j)
            acc[i][j] = __builtin_amdgcn_mfma_f32_16x16x32_bf16(af[i], bv[j], acc[i][j], 0, 0, 0);
      }
      // post-MFMA slack: GN+ReLU the freshly prefetched regs for the NEXT step
      if (FUSE) {
        if (!(icb == 3 && tap == 8)) {
          const int ntap2 = (tap == 8) ? 0 : tap + 1;
          if (tap == 8)
            gn_coeff(stT, gGt, gBt, icb + 1, qsw, invcnt, A8, C8);
#pragma unroll
          for (int t4 = 0; t4 < 4; ++t4) {
            intx4 tr = gn_relu(xr[t4], A8, C8);
            xr[t4] = ((mask9[t4] >> ntap2) & 1u) ? tr : zreg;
          }
        }
      }
    }
  }

  // epilogue; D[m=(lane>>4)*4+r][n=lane&15]
  const int quad = lane >> 4, col = lane & 15;
  if (MODE == 0) {
    u16* convB = a.outB[tower];
    float s[4] = {0.f, 0.f, 0.f, 0.f}, ss[4] = {0.f, 0.f, 0.f, 0.f};
#pragma unroll
    for (int j = 0; j < 4; ++j) {
      int pl = n0 + wn * 64 + j * 16 + col;
      bool valid = pl < P;
      u16* dst = convB + ((size_t)b * PA_TOTAL + base + pl) * CCH + mt * 128 + wm * 64 + quad * 4;
#pragma unroll
      for (int i = 0; i < 4; ++i) {
        ushort4 hv;
#pragma unroll
        for (int r = 0; r < 4; ++r) {
          u16 hh = f2bf(acc[i][j][r]);
          ((u16*)&hv)[r] = hh;
          float vr = bf2f(hh);                    // accumulate ROUNDED value -> GN self-consistent
          if (valid) { s[i] += vr; ss[i] += vr * vr; }
        }
        if (valid) *(ushort4*)(dst + i * 16) = hv;
      }
    }
#pragma unroll
    for (int i = 0; i < 4; ++i) {
#pragma unroll
      for (int off = 16; off >= 1; off >>= 1) {
        s[i] += __shfl_down(s[i], off, 64);
        ss[i] += __shfl_down(ss[i], off, 64);
      }
    }
    if ((lane & 31) == 0) {
      int half = lane >> 5;
#pragma unroll
      for (int i = 0; i < 4; ++i) {
        float* st = a.stats + tower * 640 +
                    ((size_t)((b * 5 + lvl) * 32 + mt * 16 + wm * 8 + i * 2 + half)) * 2;
        atomicAdd(st, s[i]);
        atomicAdd(st + 1, ss[i]);
      }
    }
  } else {
    float* dout = a.dout;
    if (tower == 0) {
#pragma unroll
      for (int j = 0; j < 4; ++j) {
        int pl = n0 + wn * 64 + j * 16 + col;
        if (pl >= P) continue;
        int ocb = wm * 16 + quad * 4;
#pragma unroll
        for (int r = 0; r < 4; ++r) {
          int oc = ocb + r;
          float v = acc[0][j][r];
          if (oc < 20)       dout[tb.lb[lvl] + ((size_t)b * 20 + oc) * P + pl] = v + a.biasCls[oc];
          else if (oc == 20) dout[tb.cb[lvl] + (size_t)b * P + pl] = v + a.biasCtr[0];
        }
      }
    } else {
      float sc = a.scales[lvl];
#pragma unroll
      for (int j = 0; j < 4; ++j) {
        int pl = n0 + wn * 64 + j * 16 + col;
        if (pl >= P) continue;
        int ocb = wm * 16 + quad * 4;
#pragma unroll
        for (int r = 0; r < 4; ++r) {
          int oc = ocb + r;
          if (oc < 4)
            dout[tb.bb[lvl] + ((size_t)b * 4 + oc) * P + pl] = expf((acc[0][j][r] + a.biasBox[oc]) * sc);
        }
      }
    }
  }
}

extern "C" void kernel_launch(void* const* d_in, const int* in_sizes, int n_in,
                              void* d_out, int out_size, void* d_ws, size_t ws_size,
                              hipStream_t stream) {
  const float* feat[5];
  for (int i = 0; i < 5; ++i) feat[i] = (const float*)d_in[i];
  const float* cls_tw_w  = (const float*)d_in[5];
  const float* cls_tw_g  = (const float*)d_in[6];
  const float* cls_tw_b  = (const float*)d_in[7];
  const float* box_tw_w  = (const float*)d_in[8];
  const float* box_tw_g  = (const float*)d_in[9];
  const float* box_tw_b  = (const float*)d_in[10];
  const float* cls_pred_w = (const float*)d_in[11];
  const float* cls_pred_b = (const float*)d_in[12];
  const float* box_pred_w = (const float*)d_in[13];
  const float* box_pred_b = (const float*)d_in[14];
  const float* ctr_pred_w = (const float*)d_in[15];
  const float* ctr_pred_b = (const float*)d_in[16];
  const float* scales     = (const float*)d_in[17];
  float* out = (float*)d_out;

  char* ws = (char*)d_ws;
  float* statsA = (float*)(ws + 512);                // 5120 B
  u16*   WrCls  = (u16*)(ws + 8192);                 // 1024 x 2304 bf16
  u16*   WrBox  = (u16*)(ws + 8192 + 4718592);
  u16*   WrPCls = (u16*)(ws + 9445376);              // 32 x 2304 bf16 (21 used)
  u16*   WrPBox = (u16*)(ws + 9445376 + 147456);     // 32 x 2304 bf16 (4 used)
  float* statsB = (float*)(ws + 9445376 + 2 * 147456);  // 5120 B, ends < 10625024
  u16*   bufIn  = (u16*)(ws + 10625024);
  // ping-pong RAW conv-out pairs (GN applied by the consumer's staging)
  u16*   bufB0  = (u16*)(ws + 10625024 + 1 * (size_t)14024704);
  u16*   bufB1  = (u16*)(ws + 10625024 + 2 * (size_t)14024704);
  u16*   bufA0  = (u16*)(ws + 10625024 + 3 * (size_t)14024704);
  u16*   bufA1  = (u16*)(ws + 10625024 + 4 * (size_t)14024704);

  Tables tb = { {100,50,25,13,7}, {100,50,25,13,7}, {10000,2500,625,169,49},
                {0,10112,12672,13312,13568}, {0,79,99,104,106},
                {0,400000,500000,525000,531760},
                {533720,613720,633720,638720,640072},
                {640464,660464,665464,666714,667052} };

  hipMemsetAsync(WrPCls, 0, 147456, stream);
  hipMemsetAsync(WrPBox, 0, 147456, stream);

  reorder_rows<<<1024, 256, 0, stream>>>(cls_tw_w, WrCls);
  reorder_rows<<<1024, 256, 0, stream>>>(box_tw_w, WrBox);
  reorder_pred_cls<<<21, 256, 0, stream>>>(cls_pred_w, ctr_pred_w, WrPCls);
  reorder_rows<<<4, 256, 0, stream>>>(box_pred_w, WrPBox);

  FeatPtrs fp = {{feat[0], feat[1], feat[2], feat[3], feat[4]}};
  convert_inputs<<<dim3(PA_TOTAL / 32, 8, 2), 256, 0, stream>>>(fp, bufIn, tb);

  ConvArgs a;
  a.dout = out;
  a.biasCls = cls_pred_b; a.biasCtr = ctr_pred_b; a.biasBox = box_pred_b; a.scales = scales;

  // stage s: out pair = (s even ? A : B); reads (s==0 ? bufIn : other pair)
  for (int s = 0; s < 4; ++s) {
    a.X[0] = (s == 0) ? bufIn : ((s & 1) ? bufA0 : bufB0);
    a.X[1] = (s == 0) ? bufIn : ((s & 1) ? bufA1 : bufB1);
    a.outB[0] = (s & 1) ? bufB0 : bufA0;
    a.outB[1] = (s & 1) ? bufB1 : bufA1;
    a.Wt[0] = WrCls + (size_t)s * 256 * KTOT;
    a.Wt[1] = WrBox + (size_t)s * 256 * KTOT;
    a.stats   = (s & 1) ? statsB : statsA;   // this stage's stats out
    a.statsIn = (s & 1) ? statsA : statsB;   // previous stage's stats
    int sp = (s > 0) ? (s - 1) : 0;
    a.gG[0] = cls_tw_g + sp * 256; a.gB[0] = cls_tw_b + sp * 256;
    a.gG[1] = box_tw_g + sp * 256; a.gB[1] = box_tw_b + sp * 256;
    hipMemsetAsync(a.stats, 0, 5120, stream);
    if (s == 0) conv_mfma<0, 0><<<dim3(107, 2, 4), 256, 0, stream>>>(a, tb);
    else        conv_mfma<0, 1><<<dim3(107, 2, 4), 256, 0, stream>>>(a, tb);
  }
  // pred convs: read stage-3 raw output (B pair) + stage-3 GN params
  a.X[0] = bufB0; a.X[1] = bufB1;
  a.Wt[0] = WrPCls; a.Wt[1] = WrPBox;
  a.statsIn = statsB;
  a.gG[0] = cls_tw_g + 3 * 256; a.gB[0] = cls_tw_b + 3 * 256;
  a.gG[1] = box_tw_g + 3 * 256; a.gB[1] = box_tw_b + 3 * 256;
  conv_mfma<1, 1><<<dim3(108, 2, 2), 256, 0, stream>>>(a, tb);
}

// Round 7
// 867.983 us; speedup vs baseline: 2.7526x; 1.2155x over previous
//
#include <hip/hip_runtime.h>
#include <hip/hip_bf16.h>
#include <cstdint>

typedef unsigned short u16;
typedef __attribute__((ext_vector_type(8))) short short8;
typedef __attribute__((ext_vector_type(4))) float floatx4;
typedef __attribute__((ext_vector_type(4))) int intx4;

#define PA_TOTAL 13696   // sum of per-level pixel counts, each padded to 128
#define CCH 256
#define KTOT 2304        // 9 taps * 256 ic

struct Tables {
  int H[5], W[5], P[5], base[5], tile0[5];
  int lb[5], bb[5], cb[5];   // d_out offsets: logits, bbox, centerness per level
};
struct FeatPtrs { const float* f[5]; };
struct ConvArgs {
  const u16* X[2];      // per-tower input activations
  const u16* Wt[2];     // per-tower weight matrices for this stage
  u16* outB[2];         // per-tower conv output (bf16 NHWC)
  float* stats;         // [tower][ (b*5+lvl)*32+g ][2]  -> tower stride 640 floats
  float* dout;
  const float* biasCls; const float* biasCtr; const float* biasBox; const float* scales;
};

__device__ __forceinline__ u16 f2bf(float f) {
  union { float f; unsigned u; } v; v.f = f;
  unsigned r = v.u + 0x7fffu + ((v.u >> 16) & 1u);   // RNE
  return (u16)(r >> 16);
}
__device__ __forceinline__ float bf2f(u16 h) {
  union { unsigned u; float f; } v; v.u = ((unsigned)h) << 16;
  return v.f;
}

// async global->LDS: 16B per lane, dest = wave-uniform base + lane*16.
__device__ __forceinline__ void gload16(const void* g, void* l) {
  __builtin_amdgcn_global_load_lds(
      (const __attribute__((address_space(1))) void*)g,
      (__attribute__((address_space(3))) void*)l, 16, 0, 0);
}

// ---- weight reorder, coalesced: one block per row; read row [256 ic][9 tap] f32
// contiguously into LDS, write [9 tap][256 ic] bf16 contiguously.
__global__ void reorder_rows(const float* __restrict__ src, u16* __restrict__ out) {
  __shared__ float row[KTOT];
  const int r = blockIdx.x;
  const float* s = src + (size_t)r * KTOT;
  u16* o = out + (size_t)r * KTOT;
#pragma unroll
  for (int j = 0; j < 9; ++j) row[threadIdx.x + j * 256] = s[threadIdx.x + j * 256];
  __syncthreads();
#pragma unroll
  for (int j = 0; j < 9; ++j) {
    int k = threadIdx.x + j * 256;
    o[k] = f2bf(row[(k & 255) * 9 + (k >> 8)]);
  }
}

// cls_pred (20 rows) + ctr_pred (1 row) combined into 21-row weight matrix
__global__ void reorder_pred_cls(const float* __restrict__ cls_w, const float* __restrict__ ctr_w,
                                 u16* __restrict__ out) {
  __shared__ float row[KTOT];
  const int r = blockIdx.x;   // 0..20
  const float* s = (r < 20) ? (cls_w + (size_t)r * KTOT) : ctr_w;
  u16* o = out + (size_t)r * KTOT;
#pragma unroll
  for (int j = 0; j < 9; ++j) row[threadIdx.x + j * 256] = s[threadIdx.x + j * 256];
  __syncthreads();
#pragma unroll
  for (int j = 0; j < 9; ++j) {
    int k = threadIdx.x + j * 256;
    o[k] = f2bf(row[(k & 255) * 9 + (k >> 8)]);
  }
}

// ---- inputs NCHW f32 -> NHWC bf16, 32x32 LDS transpose (coalesced both sides)
// grid: (PA_TOTAL/32, 8, 2)  block 256. Pixel-padding rows written as ZERO
// (they are the conv staging's halo redirect target).
__global__ void convert_inputs(FeatPtrs fp, u16* __restrict__ out, Tables tb) {
  __shared__ float tile[32][33];
  const int pt = blockIdx.x, c32 = blockIdx.y, b = blockIdx.z;
  const int p0 = pt * 32;
  int lvl = 0;
#pragma unroll
  for (int i = 1; i < 5; ++i) if (p0 >= tb.base[i]) lvl = i;
  const int P = tb.P[lvl];
  const int pl0 = p0 - tb.base[lvl];
  const int r = threadIdx.x >> 5, col = threadIdx.x & 31;
  const float* src = fp.f[lvl] + ((size_t)b * CCH + c32 * 32) * P;
#pragma unroll
  for (int i = 0; i < 4; ++i) {
    int crow = r + i * 8;
    int pl = pl0 + col;
    tile[crow][col] = (pl < P) ? src[(size_t)crow * P + pl] : 0.f;
  }
  __syncthreads();
#pragma unroll
  for (int i = 0; i < 4; ++i) {
    int px = r + i * 8;
    out[((size_t)b * PA_TOTAL + p0 + px) * CCH + c32 * 32 + col] = f2bf(tile[col][px]);
  }
}

// ---- implicit-GEMM conv3x3 SAME, bf16 MFMA 16x16x32, BK=64, 128-px tiles.
// OCCUPANCY 4 -> 5 blocks/CU (evidence: dur tracks resident blocks linearly;
// pipe demand ~half of step wall -> latency-exposure-bound). The baseline's
// 120 VGPR (xr[4]+wr[4] staging regs) capped waves at 4/SIMD. Fix: stage BOTH
// X and W via global_load_lds, single-buffered. Both dests are wave-uniform
// base + lane*16 with the XOR swizzle pre-folded into the per-lane GLOBAL
// source (rule 21) -> LDS image bit-identical to the proven baseline; readers
// unchanged. Deletes 32 staging VGPRs and all 32 ds_writes per block-step.
// Uniform step body: __syncthreads -> issue NI W-gloads + 4 X-gloads ->
// vmcnt(0)+s_barrier -> MFMA. 5 phase-staggered blocks/CU hide the drain.
// R6 FIX: X and W live in ONE contiguous __shared__ array - the R5 submission
// addressed W's DMA dest as ldsX+16384 while reading via a separate ldsW
// symbol; LDS symbol order is not guaranteed -> potential OOB LDS write from
// the DMA engine (likely cause of the container fault). Single symbol + fixed
// offsets removes the hazard.
// Halo-invalid lanes redirect their source OFFSET to the level's zero
// pixel-padding rows (bufIn zeroed by convert_inputs, bufAct pads zeroed by
// gn_norm) - load always issues, LDS slots get real zeros.
// MODE 0: 128x128 tile, tower stage -> bf16 NHWC + fused GN stats. grid (107,2,4).
// MODE 1: 32x128 tile (21/4 real oc rows), pred convs -> d_out NCHW. grid (108,2,2).
template <int MODE>
__global__ __launch_bounds__(256, 5) void conv_mfma(ConvArgs a, Tables tb) {
  constexpr int NI = (MODE == 0) ? 4 : 1;     // A-frag rows per wave
  constexpr int WROWS = (MODE == 0) ? 128 : 32;
  const int L = blockIdx.x + (MODE == 0 ? 107 : 108) * (blockIdx.y + 2 * blockIdx.z);
  const int xcd = L & 7, slot = L >> 3;
  int tower, mt, b, t;
  if (MODE == 0) {
    tower = xcd >> 2; mt = (xcd >> 1) & 1; b = xcd & 1; t = slot;
  } else {
    tower = xcd >> 2; mt = 0; b = (xcd >> 1) & 1; t = slot * 2 + (xcd & 1);
    if (t >= 107) return;
  }
  int lvl = 0;
#pragma unroll
  for (int i = 1; i < 5; ++i) if (t >= tb.tile0[i]) lvl = i;
  const int H = tb.H[lvl], W = tb.W[lvl], P = tb.P[lvl], base = tb.base[lvl];
  const int n0 = (t - tb.tile0[lvl]) * 128;

  const int tid = threadIdx.x;
  const int lane = tid & 63, wv = tid >> 6;
  const int wm = wv >> 1, wn = wv & 1;

  // ONE contiguous LDS block: X tile at [0, 16384) bytes, W tile after it.
  __shared__ u16 ldsAll[128 * 64 + WROWS * 64];
  u16* ldsX = ldsAll;                 // [px][64 ic] swizzled, 16KB
  u16* ldsW = ldsAll + 128 * 64;      // [oc][64 k] swizzled

  const u16* X = a.X[tower];
  const u16* Wt = a.Wt[tower];
  const char* Xb = (const char*)(X + ((size_t)b * PA_TOTAL + base) * CCH);
  const char* Wb = (const char*)(Wt + (size_t)(MODE == 0 ? mt * 128 : 0) * KTOT);

  // staging geometry: chunk ci = (t4*4+wv)*64 + lane -> row=ci>>3, col=lane&7;
  // slot (row,col) holds k-chunk q' = col ^ (row&7) -> swizzle pre-folded into
  // the per-lane GLOBAL byte offset qsw2; LDS dest is linear lane*16.
  const int qsw2 = ((lane & 7) ^ (lane >> 3)) * 16;   // byte offset of fetched chunk
  int xoffG[4];                      // per-lane global byte offsets (row term)
  unsigned mask9[4];
  int xlds[4];                       // wave-uniform LDS byte bases
#pragma unroll
  for (int t4 = 0; t4 < 4; ++t4) {
    int row = (t4 * 4 + wv) * 8 + (lane >> 3);
    int prow = n0 + row;
    int rr = prow / W, cc = prow - rr * W;
    unsigned m = 0;
#pragma unroll
    for (int tap = 0; tap < 9; ++tap) {
      const int dh = tap / 3 - 1, dw = tap % 3 - 1;
      bool v = ((unsigned)(rr + dh) < (unsigned)H) & ((unsigned)(cc + dw) < (unsigned)W);
      m |= ((unsigned)v) << tap;
    }
    mask9[t4] = m;
    xoffG[t4] = prow * (CCH * 2) + qsw2;
    xlds[t4] = (t4 * 4 + wv) * 1024;
  }
  const int padoff = P * (CCH * 2) + qsw2;   // zero pixel-padding row (halo target)
  int woffG[NI];
  int wlds[NI];                      // wave-uniform byte base within W region
#pragma unroll
  for (int e = 0; e < NI; ++e) {
    int wrow = (MODE == 0) ? ((e * 4 + wv) * 8 + (lane >> 3)) : (wv * 8 + (lane >> 3));
    woffG[e] = wrow * (KTOT * 2) + qsw2;
    wlds[e] = 16384 + ((MODE == 0) ? ((e * 4 + wv) * 1024) : (wv * 1024));
  }

  // fragment LDS offsets (u16), reader swizzle col = kq ^ (row&7);
  // h=1 offsets are h=0 ^ 32 elems (bit-2 of kq scaled by 8; no carry).
  const int arow = lane & 15, rsw = lane & 7, kq0 = lane >> 4;
  const int csw0 = (kq0 ^ rsw) * 8;
  int aoff[NI], boff[4];
#pragma unroll
  for (int i = 0; i < NI; ++i) {
    int rowb = (MODE == 0) ? (wm * 64 + i * 16) : (wm * 16);
    aoff[i] = (rowb + arow) * 64 + csw0;
  }
#pragma unroll
  for (int i = 0; i < 4; ++i) boff[i] = (wn * 64 + i * 16 + arow) * 64 + csw0;

  floatx4 acc[NI][4];
#pragma unroll
  for (int i = 0; i < NI; ++i)
#pragma unroll
    for (int j = 0; j < 4; ++j) acc[i][j] = (floatx4)0.f;

  // K-loop: icb outer, taps inner (unrolled). Uniform step body; all staging
  // is async DMA, no staging registers, no ds_writes.
#pragma unroll 1
  for (int icb = 0; icb < 4; ++icb) {
#pragma unroll
    for (int tap = 0; tap < 9; ++tap) {
      __syncthreads();   // all waves done reading LDS of previous step
      const int ko = (tap * 256 + icb * 64) * 2;                 // W byte off, uniform
      const int dh = tap / 3 - 1, dw = tap % 3 - 1;
      const int doff = (dh * W + dw) * (CCH * 2) + icb * 128;    // X byte off, uniform
#pragma unroll
      for (int e = 0; e < NI; ++e)
        gload16(Wb + woffG[e] + ko, (char*)ldsAll + wlds[e]);
#pragma unroll
      for (int t4 = 0; t4 < 4; ++t4) {
        const int off = ((mask9[t4] >> tap) & 1u) ? (xoffG[t4] + doff) : padoff;
        gload16(Xb + off, (char*)ldsAll + xlds[t4]);
      }
      // all 4+NI gloads must land block-wide before MFMA reads LDS
      asm volatile("s_waitcnt vmcnt(0) lgkmcnt(0)\n\ts_barrier" ::: "memory");
      __builtin_amdgcn_s_setprio(1);
#pragma unroll
      for (int h = 0; h < 2; ++h) {
        const int hx = h * 32;
        short8 af[NI], bv[4];
#pragma unroll
        for (int i = 0; i < NI; ++i) af[i] = *(const short8*)(ldsW + (aoff[i] ^ hx));
#pragma unroll
        for (int j = 0; j < 4; ++j) bv[j] = *(const short8*)(ldsX + (boff[j] ^ hx));
#pragma unroll
        for (int i = 0; i < NI; ++i)
#pragma unroll
          for (int j = 0; j < 4; ++j)
            acc[i][j] = __builtin_amdgcn_mfma_f32_16x16x32_bf16(af[i], bv[j], acc[i][j], 0, 0, 0);
      }
      __builtin_amdgcn_s_setprio(0);
    }
  }

  // epilogue; D[m=(lane>>4)*4+r][n=lane&15]
  const int quad = lane >> 4, col = lane & 15;
  if (MODE == 0) {
    u16* convB = a.outB[tower];
    float s[4] = {0.f, 0.f, 0.f, 0.f}, ss[4] = {0.f, 0.f, 0.f, 0.f};
#pragma unroll
    for (int j = 0; j < 4; ++j) {
      int pl = n0 + wn * 64 + j * 16 + col;
      bool valid = pl < P;
      u16* dst = convB + ((size_t)b * PA_TOTAL + base + pl) * CCH + mt * 128 + wm * 64 + quad * 4;
#pragma unroll
      for (int i = 0; i < 4; ++i) {
        ushort4 hv;
#pragma unroll
        for (int r = 0; r < 4; ++r) {
          u16 hh = f2bf(acc[i][j][r]);
          ((u16*)&hv)[r] = hh;
          float vr = bf2f(hh);                    // accumulate ROUNDED value -> GN self-consistent
          if (valid) { s[i] += vr; ss[i] += vr * vr; }
        }
        if (valid) *(ushort4*)(dst + i * 16) = hv;
      }
    }
#pragma unroll
    for (int i = 0; i < 4; ++i) {
#pragma unroll
      for (int off = 16; off >= 1; off >>= 1) {
        s[i] += __shfl_down(s[i], off, 64);
        ss[i] += __shfl_down(ss[i], off, 64);
      }
    }
    if ((lane & 31) == 0) {
      int half = lane >> 5;
#pragma unroll
      for (int i = 0; i < 4; ++i) {
        float* st = a.stats + tower * 640 +
                    ((size_t)((b * 5 + lvl) * 32 + mt * 16 + wm * 8 + i * 2 + half)) * 2;
        atomicAdd(st, s[i]);
        atomicAdd(st + 1, ss[i]);
      }
    }
  } else {
    float* dout = a.dout;
    if (tower == 0) {
#pragma unroll
      for (int j = 0; j < 4; ++j) {
        int pl = n0 + wn * 64 + j * 16 + col;
        if (pl >= P) continue;
        int ocb = wm * 16 + quad * 4;
#pragma unroll
        for (int r = 0; r < 4; ++r) {
          int oc = ocb + r;
          float v = acc[0][j][r];
          if (oc < 20)       dout[tb.lb[lvl] + ((size_t)b * 20 + oc) * P + pl] = v + a.biasCls[oc];
          else if (oc == 20) dout[tb.cb[lvl] + (size_t)b * P + pl] = v + a.biasCtr[0];
        }
      }
    } else {
      float sc = a.scales[lvl];
#pragma unroll
      for (int j = 0; j < 4; ++j) {
        int pl = n0 + wn * 64 + j * 16 + col;
        if (pl >= P) continue;
        int ocb = wm * 16 + quad * 4;
#pragma unroll
        for (int r = 0; r < 4; ++r) {
          int oc = ocb + r;
          if (oc < 4)
            dout[tb.bb[lvl] + ((size_t)b * 4 + oc) * P + pl] = expf((acc[0][j][r] + a.biasBox[oc]) * sc);
        }
      }
    }
  }
}

// ---- GroupNorm pass 2: normalize + affine + ReLU, bf16 -> bf16, coalesced; both towers.
// grid (3424, 2): y = tower. Pixel-padding rows ZEROED (conv halo redirect target).
__global__ void gn_norm(const u16* __restrict__ c0, const u16* __restrict__ c1,
                        const float* __restrict__ stats,
                        const float* __restrict__ g0, const float* __restrict__ b0,
                        const float* __restrict__ g1, const float* __restrict__ b1,
                        u16* __restrict__ a0, u16* __restrict__ a1, Tables tb) {
  const int tower = blockIdx.y;
  const u16* convB = tower ? c1 : c0;
  const float* gamma = tower ? g1 : g0;
  const float* beta = tower ? b1 : b0;
  u16* act = tower ? a1 : a0;
  int idx = blockIdx.x * 256 + threadIdx.x;
  int c8 = idx & 31;                 // == group index
  int rest = idx >> 5;
  int p = rest % PA_TOTAL;
  int b = rest / PA_TOTAL;
  int lvl = 0;
#pragma unroll
  for (int i = 1; i < 5; ++i) if (p >= tb.base[i]) lvl = i;
  if (p - tb.base[lvl] >= tb.P[lvl]) {
    short8 z = (short8)(short)0;
    *(short8*)(act + ((size_t)b * PA_TOTAL + p) * CCH + c8 * 8) = z;
    return;
  }
  const float* st = stats + tower * 640 + ((size_t)((b * 5 + lvl) * 32 + c8)) * 2;
  float cnt = 8.f * (float)tb.P[lvl];
  float mean = st[0] / cnt;
  float var = st[1] / cnt - mean * mean;
  float inv = rsqrtf(var + 1e-5f);
  const short8 x = *(const short8*)(convB + ((size_t)b * PA_TOTAL + p) * CCH + c8 * 8);
  short8 o;
#pragma unroll
  for (int j = 0; j < 8; ++j) {
    float v = bf2f((u16)x[j]);
    float y = (v - mean) * inv * gamma[c8 * 8 + j] + beta[c8 * 8 + j];
    y = fmaxf(y, 0.f);
    o[j] = (short)f2bf(y);
  }
  *(short8*)(act + ((size_t)b * PA_TOTAL + p) * CCH + c8 * 8) = o;
}

extern "C" void kernel_launch(void* const* d_in, const int* in_sizes, int n_in,
                              void* d_out, int out_size, void* d_ws, size_t ws_size,
                              hipStream_t stream) {
  const float* feat[5];
  for (int i = 0; i < 5; ++i) feat[i] = (const float*)d_in[i];
  const float* cls_tw_w  = (const float*)d_in[5];
  const float* cls_tw_g  = (const float*)d_in[6];
  const float* cls_tw_b  = (const float*)d_in[7];
  const float* box_tw_w  = (const float*)d_in[8];
  const float* box_tw_g  = (const float*)d_in[9];
  const float* box_tw_b  = (const float*)d_in[10];
  const float* cls_pred_w = (const float*)d_in[11];
  const float* cls_pred_b = (const float*)d_in[12];
  const float* box_pred_w = (const float*)d_in[13];
  const float* box_pred_b = (const float*)d_in[14];
  const float* ctr_pred_w = (const float*)d_in[15];
  const float* ctr_pred_b = (const float*)d_in[16];
  const float* scales     = (const float*)d_in[17];
  float* out = (float*)d_out;

  char* ws = (char*)d_ws;
  float* stats  = (float*)(ws + 512);                // 5120 B
  u16*   WrCls  = (u16*)(ws + 8192);                 // 1024 x 2304 bf16
  u16*   WrBox  = (u16*)(ws + 8192 + 4718592);
  u16*   WrPCls = (u16*)(ws + 9445376);              // 32 x 2304 bf16 (21 used)
  u16*   WrPBox = (u16*)(ws + 9445376 + 147456);     // 32 x 2304 bf16 (4 used)
  u16*   bufIn   = (u16*)(ws + 10625024);
  u16*   bufAct0 = (u16*)(ws + 10625024 + 1 * (size_t)14024704);
  u16*   bufAct1 = (u16*)(ws + 10625024 + 2 * (size_t)14024704);
  u16*   bufCv0  = (u16*)(ws + 10625024 + 3 * (size_t)14024704);
  u16*   bufCv1  = (u16*)(ws + 10625024 + 4 * (size_t)14024704);

  Tables tb = { {100,50,25,13,7}, {100,50,25,13,7}, {10000,2500,625,169,49},
                {0,10112,12672,13312,13568}, {0,79,99,104,106},
                {0,400000,500000,525000,531760},
                {533720,613720,633720,638720,640072},
                {640464,660464,665464,666714,667052} };

  hipMemsetAsync(WrPCls, 0, 147456, stream);
  hipMemsetAsync(WrPBox, 0, 147456, stream);

  reorder_rows<<<1024, 256, 0, stream>>>(cls_tw_w, WrCls);
  reorder_rows<<<1024, 256, 0, stream>>>(box_tw_w, WrBox);
  reorder_pred_cls<<<21, 256, 0, stream>>>(cls_pred_w, ctr_pred_w, WrPCls);
  reorder_rows<<<4, 256, 0, stream>>>(box_pred_w, WrPBox);

  FeatPtrs fp = {{feat[0], feat[1], feat[2], feat[3], feat[4]}};
  convert_inputs<<<dim3(PA_TOTAL / 32, 8, 2), 256, 0, stream>>>(fp, bufIn, tb);

  ConvArgs a;
  a.stats = stats; a.dout = out;
  a.biasCls = cls_pred_b; a.biasCtr = ctr_pred_b; a.biasBox = box_pred_b; a.scales = scales;
  a.outB[0] = bufCv0; a.outB[1] = bufCv1;

  for (int s = 0; s < 4; ++s) {
    a.X[0] = (s == 0) ? bufIn : bufAct0;
    a.X[1] = (s == 0) ? bufIn : bufAct1;
    a.Wt[0] = WrCls + (size_t)s * 256 * KTOT;
    a.Wt[1] = WrBox + (size_t)s * 256 * KTOT;
    hipMemsetAsync(stats, 0, 5120, stream);
    conv_mfma<0><<<dim3(107, 2, 4), 256, 0, stream>>>(a, tb);
    gn_norm<<<dim3(3424, 2), 256, 0, stream>>>(bufCv0, bufCv1, stats,
                                               cls_tw_g + s * 256, cls_tw_b + s * 256,
                                               box_tw_g + s * 256, box_tw_b + s * 256,
                                               bufAct0, bufAct1, tb);
  }
  a.X[0] = bufAct0; a.X[1] = bufAct1;
  a.Wt[0] = WrPCls; a.Wt[1] = WrPBox;
  conv_mfma<1><<<dim3(108, 2, 2), 256, 0, stream>>>(a, tb);
}

// Round 8
// 630.630 us; speedup vs baseline: 3.7886x; 1.3764x over previous
//
#include <hip/hip_runtime.h>
#include <hip/hip_bf16.h>
#include <cstdint>

typedef unsigned short u16;
typedef __attribute__((ext_vector_type(8))) short short8;
typedef __attribute__((ext_vector_type(4))) float floatx4;
typedef __attribute__((ext_vector_type(4))) int intx4;

#define PA_TOTAL 13696   // sum of per-level pixel counts, each padded to 128
#define CCH 256
#define KTOT 2304        // 9 taps * 256 ic

struct Tables {
  int H[5], W[5], P[5], base[5], tile0[5];
  int lb[5], bb[5], cb[5];   // d_out offsets: logits, bbox, centerness per level
};
struct FeatPtrs { const float* f[5]; };
struct ConvArgs {
  const u16* X[2];      // per-tower input activations
  const u16* Wt[2];     // per-tower weight matrices for this stage
  u16* outB[2];         // per-tower conv output (bf16 NHWC)
  float* stats;         // [tower][ (b*5+lvl)*32+g ][2]  -> tower stride 640 floats
  float* dout;
  const float* biasCls; const float* biasCtr; const float* biasBox; const float* scales;
};
struct ReorderArgs {
  const float* cls_w; const float* box_w; const float* pcls_w; const float* ctr_w; const float* pbox_w;
  u16* wrCls; u16* wrBox; u16* wrPCls; u16* wrPBox;
};

__device__ __forceinline__ u16 f2bf(float f) {
  union { float f; unsigned u; } v; v.f = f;
  unsigned r = v.u + 0x7fffu + ((v.u >> 16) & 1u);   // RNE
  return (u16)(r >> 16);
}
__device__ __forceinline__ float bf2f(u16 h) {
  union { unsigned u; float f; } v; v.u = ((unsigned)h) << 16;
  return v.f;
}

// ---- ALL weight reordering in ONE launch (was 4 kernels + 2 memsets).
// rows 0..1023: cls tower; 1024..2047: box tower; 2048..2067: cls_pred;
// 2068: ctr_pred (row 20 of pred-cls matrix); 2069..2072: box_pred;
// 2073..2083: zero pred-cls rows 21..31; 2084..2111: zero pred-box rows 4..31.
// Reorder body: read row [256 ic][9 tap] f32 contiguously into LDS, write
// [9 tap][256 ic] bf16 contiguously. LDS read stride 9 floats -> conflict-free.
__global__ void reorder_all(ReorderArgs ra) {
  __shared__ float row[KTOT];
  const int r = blockIdx.x;
  const float* s;
  u16* o;
  if (r < 1024)      { s = ra.cls_w  + (size_t)r * KTOT;          o = ra.wrCls  + (size_t)r * KTOT; }
  else if (r < 2048) { int q = r - 1024; s = ra.box_w  + (size_t)q * KTOT; o = ra.wrBox  + (size_t)q * KTOT; }
  else if (r < 2068) { int q = r - 2048; s = ra.pcls_w + (size_t)q * KTOT; o = ra.wrPCls + (size_t)q * KTOT; }
  else if (r == 2068){ s = ra.ctr_w;                               o = ra.wrPCls + (size_t)20 * KTOT; }
  else if (r < 2073) { int q = r - 2069; s = ra.pbox_w + (size_t)q * KTOT; o = ra.wrPBox + (size_t)q * KTOT; }
  else if (r < 2084) {
    u16* oz = ra.wrPCls + (size_t)(21 + (r - 2073)) * KTOT;
#pragma unroll
    for (int j = 0; j < 9; ++j) oz[threadIdx.x + j * 256] = 0;
    return;
  } else {
    u16* oz = ra.wrPBox + (size_t)(4 + (r - 2084)) * KTOT;
#pragma unroll
    for (int j = 0; j < 9; ++j) oz[threadIdx.x + j * 256] = 0;
    return;
  }
#pragma unroll
  for (int j = 0; j < 9; ++j) row[threadIdx.x + j * 256] = s[threadIdx.x + j * 256];
  __syncthreads();
#pragma unroll
  for (int j = 0; j < 9; ++j) {
    int k = threadIdx.x + j * 256;
    o[k] = f2bf(row[(k & 255) * 9 + (k >> 8)]);
  }
}

// ---- inputs NCHW f32 -> NHWC bf16, 32x32 LDS transpose (coalesced both sides)
// grid: (PA_TOTAL/32, 8, 2)  block 256
__global__ void convert_inputs(FeatPtrs fp, u16* __restrict__ out, Tables tb) {
  __shared__ float tile[32][33];
  const int pt = blockIdx.x, c32 = blockIdx.y, b = blockIdx.z;
  const int p0 = pt * 32;
  int lvl = 0;
#pragma unroll
  for (int i = 1; i < 5; ++i) if (p0 >= tb.base[i]) lvl = i;
  const int P = tb.P[lvl];
  const int pl0 = p0 - tb.base[lvl];
  const int r = threadIdx.x >> 5, col = threadIdx.x & 31;
  const float* src = fp.f[lvl] + ((size_t)b * CCH + c32 * 32) * P;
#pragma unroll
  for (int i = 0; i < 4; ++i) {
    int crow = r + i * 8;
    int pl = pl0 + col;
    tile[crow][col] = (pl < P) ? src[(size_t)crow * P + pl] : 0.f;
  }
  __syncthreads();
#pragma unroll
  for (int i = 0; i < 4; ++i) {
    int px = r + i * 8;
    out[((size_t)b * PA_TOTAL + p0 + px) * CCH + c32 * 32 + col] = f2bf(tile[col][px]);
  }
}

// ---- implicit-GEMM conv3x3 SAME, bf16 MFMA 16x16x32, BK=64, 128-px tiles.
// EXACT R0-baseline structure (639.6us measured): XOR-swizzled 32KB LDS,
// register-staged 1-step prefetch, 2x __syncthreads per step, towers merged.
// 8 structural perturbations (dbuf, no-drain, no-LDS, GN-fusion x2,
// gload_lds+occupancy x2) all measured worse; reg-count arithmetic shows this
// geometry needs ~120-130 VGPR -> 4 waves/SIMD is the no-spill ceiling ->
// this is the validated local optimum for the conv loop.
// MODE 0: 128x128 tile, tower stage -> bf16 NHWC + fused GN stats. grid (107,2,4).
// MODE 1: 32x128 tile (21/4 real oc rows), pred convs -> d_out NCHW.
//         grid (108,2,2) = 432 = 54*8 (4 blocks guard out).
template <int MODE>
__global__ __launch_bounds__(256) void conv_mfma(ConvArgs a, Tables tb) {
  constexpr int NI = (MODE == 0) ? 4 : 1;     // A-frag rows per wave
  const int L = blockIdx.x + (MODE == 0 ? 107 : 108) * (blockIdx.y + 2 * blockIdx.z);
  const int xcd = L & 7, slot = L >> 3;
  int tower, mt, b, t;
  if (MODE == 0) {
    tower = xcd >> 2; mt = (xcd >> 1) & 1; b = xcd & 1; t = slot;
  } else {
    tower = xcd >> 2; mt = 0; b = (xcd >> 1) & 1; t = slot * 2 + (xcd & 1);
    if (t >= 107) return;
  }
  int lvl = 0;
#pragma unroll
  for (int i = 1; i < 5; ++i) if (t >= tb.tile0[i]) lvl = i;
  const int H = tb.H[lvl], W = tb.W[lvl], P = tb.P[lvl], base = tb.base[lvl];
  const int n0 = (t - tb.tile0[lvl]) * 128;

  const int tid = threadIdx.x;
  const int lane = tid & 63, wv = tid >> 6;
  const int wm = wv >> 1, wn = wv & 1;

  __shared__ u16 ldsX[128 * 64];                       // [px][64 ic] swizzled, 16KB
  __shared__ u16 ldsW[(MODE == 0 ? 128 : 32) * 64];    // [oc][64 k] swizzled

  const u16* X = a.X[tower];
  const u16* Wt = a.Wt[tower];

  // staging geometry: chunk ci = (t4*4+wv)*64 + lane -> row=ci>>3, col=lane&7;
  // slot (row,col) holds k-chunk q' = col ^ (row&7), a per-thread constant.
  const int qsw = (((lane & 7) ^ (lane >> 3))) * 8;   // u16 offset of fetched chunk
  int prow[4];
  unsigned mask9[4];
  int xdst[4];                       // per-lane LDS byte dests
#pragma unroll
  for (int t4 = 0; t4 < 4; ++t4) {
    int row = (t4 * 4 + wv) * 8 + (lane >> 3);
    prow[t4] = n0 + row;
    int rr = prow[t4] / W, cc = prow[t4] - rr * W;
    unsigned m = 0;
#pragma unroll
    for (int tap = 0; tap < 9; ++tap) {
      const int dh = tap / 3 - 1, dw = tap % 3 - 1;
      bool v = ((unsigned)(rr + dh) < (unsigned)H) & ((unsigned)(cc + dw) < (unsigned)W);
      m |= ((unsigned)v) << tap;
    }
    mask9[t4] = m;
    xdst[t4] = (t4 * 4 + wv) * 1024 + lane * 16;
  }
  const u16* wsrc[NI];
  int wdst[NI];
#pragma unroll
  for (int e = 0; e < NI; ++e) {
    int wrow = (MODE == 0) ? ((e * 4 + wv) * 8 + (lane >> 3)) : (wv * 8 + (lane >> 3));
    wsrc[e] = Wt + (size_t)(mt * 128 + wrow) * KTOT + qsw;
    wdst[e] = (MODE == 0) ? xdst[e] : (wv * 1024 + lane * 16);
  }
  const u16* Xbp = X + ((size_t)b * PA_TOTAL + base) * CCH;

  // fragment LDS offsets (u16), reader swizzle col = kq ^ (row&7)
  const int arow = lane & 15, rsw = lane & 7, kq0 = lane >> 4;
  int aoff[2][NI], boff[2][4];
#pragma unroll
  for (int h = 0; h < 2; ++h) {
    int csw = (((h * 4 + kq0) ^ rsw)) * 8;
#pragma unroll
    for (int i = 0; i < NI; ++i) {
      int rowb = (MODE == 0) ? (wm * 64 + i * 16) : (wm * 16);
      aoff[h][i] = (rowb + arow) * 64 + csw;
    }
#pragma unroll
    for (int i = 0; i < 4; ++i) boff[h][i] = (wn * 64 + i * 16 + arow) * 64 + csw;
  }

  floatx4 acc[NI][4];
#pragma unroll
  for (int i = 0; i < NI; ++i)
#pragma unroll
    for (int j = 0; j < 4; ++j) acc[i][j] = (floatx4)0.f;

  const intx4 zreg = {0, 0, 0, 0};
  intx4 xr[4], wr[NI];
  // prologue: issue loads for step (icb=0, tap=0); dpos = -W-1
  {
    const int dpos0 = -W - 1;
#pragma unroll
    for (int t4 = 0; t4 < 4; ++t4)
      xr[t4] = (mask9[t4] & 1)
          ? *(const intx4*)(Xbp + (size_t)(prow[t4] + dpos0) * CCH + qsw) : zreg;
#pragma unroll
    for (int e = 0; e < NI; ++e) wr[e] = *(const intx4*)(wsrc[e]);
  }

  // K-loop: icb outer, taps inner (unrolled). Per step: barrier (prev readers
  // done) -> ds_write staged regs (vmcnt wait here, loads are 1 step old) ->
  // issue next step's loads -> barrier (writes visible) -> MFMA.
#pragma unroll 1
  for (int icb = 0; icb < 4; ++icb) {
#pragma unroll
    for (int tap = 0; tap < 9; ++tap) {
      __syncthreads();
#pragma unroll
      for (int t4 = 0; t4 < 4; ++t4) *(intx4*)((char*)ldsX + xdst[t4]) = xr[t4];
#pragma unroll
      for (int e = 0; e < NI; ++e) *(intx4*)((char*)ldsW + wdst[e]) = wr[e];
      if (!(icb == 3 && tap == 8)) {
        const int ntap = (tap == 8) ? 0 : tap + 1;
        const int nicb = (tap == 8) ? icb + 1 : icb;
        const int ndh = ntap / 3;
        const int ndpos = (ndh - 1) * W + (ntap - 3 * ndh - 1);
        const int nko = ntap * 256 + nicb * 64;
#pragma unroll
        for (int t4 = 0; t4 < 4; ++t4)
          xr[t4] = ((mask9[t4] >> ntap) & 1)
              ? *(const intx4*)(Xbp + (size_t)(prow[t4] + ndpos) * CCH + qsw + nicb * 64) : zreg;
#pragma unroll
        for (int e = 0; e < NI; ++e) wr[e] = *(const intx4*)(wsrc[e] + nko);
      }
      __syncthreads();
#pragma unroll
      for (int h = 0; h < 2; ++h) {
        short8 af[NI], bv[4];
#pragma unroll
        for (int i = 0; i < NI; ++i) af[i] = *(const short8*)(ldsW + aoff[h][i]);
#pragma unroll
        for (int j = 0; j < 4; ++j) bv[j] = *(const short8*)(ldsX + boff[h][j]);
#pragma unroll
        for (int i = 0; i < NI; ++i)
#pragma unroll
          for (int j = 0; j < 4; ++j)
            acc[i][j] = __builtin_amdgcn_mfma_f32_16x16x32_bf16(af[i], bv[j], acc[i][j], 0, 0, 0);
      }
    }
  }

  // epilogue; D[m=(lane>>4)*4+r][n=lane&15]
  const int quad = lane >> 4, col = lane & 15;
  if (MODE == 0) {
    u16* convB = a.outB[tower];
    float s[4] = {0.f, 0.f, 0.f, 0.f}, ss[4] = {0.f, 0.f, 0.f, 0.f};
#pragma unroll
    for (int j = 0; j < 4; ++j) {
      int pl = n0 + wn * 64 + j * 16 + col;
      bool valid = pl < P;
      u16* dst = convB + ((size_t)b * PA_TOTAL + base + pl) * CCH + mt * 128 + wm * 64 + quad * 4;
#pragma unroll
      for (int i = 0; i < 4; ++i) {
        ushort4 hv;
#pragma unroll
        for (int r = 0; r < 4; ++r) {
          u16 hh = f2bf(acc[i][j][r]);
          ((u16*)&hv)[r] = hh;
          float vr = bf2f(hh);                    // accumulate ROUNDED value -> GN self-consistent
          if (valid) { s[i] += vr; ss[i] += vr * vr; }
        }
        if (valid) *(ushort4*)(dst + i * 16) = hv;
      }
    }
#pragma unroll
    for (int i = 0; i < 4; ++i) {
#pragma unroll
      for (int off = 16; off >= 1; off >>= 1) {
        s[i] += __shfl_down(s[i], off, 64);
        ss[i] += __shfl_down(ss[i], off, 64);
      }
    }
    if ((lane & 31) == 0) {
      int half = lane >> 5;
#pragma unroll
      for (int i = 0; i < 4; ++i) {
        float* st = a.stats + tower * 640 +
                    ((size_t)((b * 5 + lvl) * 32 + mt * 16 + wm * 8 + i * 2 + half)) * 2;
        atomicAdd(st, s[i]);
        atomicAdd(st + 1, ss[i]);
      }
    }
  } else {
    float* dout = a.dout;
    if (tower == 0) {
#pragma unroll
      for (int j = 0; j < 4; ++j) {
        int pl = n0 + wn * 64 + j * 16 + col;
        if (pl >= P) continue;
        int ocb = wm * 16 + quad * 4;
#pragma unroll
        for (int r = 0; r < 4; ++r) {
          int oc = ocb + r;
          float v = acc[0][j][r];
          if (oc < 20)       dout[tb.lb[lvl] + ((size_t)b * 20 + oc) * P + pl] = v + a.biasCls[oc];
          else if (oc == 20) dout[tb.cb[lvl] + (size_t)b * P + pl] = v + a.biasCtr[0];
        }
      }
    } else {
      float sc = a.scales[lvl];
#pragma unroll
      for (int j = 0; j < 4; ++j) {
        int pl = n0 + wn * 64 + j * 16 + col;
        if (pl >= P) continue;
        int ocb = wm * 16 + quad * 4;
#pragma unroll
        for (int r = 0; r < 4; ++r) {
          int oc = ocb + r;
          if (oc < 4)
            dout[tb.bb[lvl] + ((size_t)b * 4 + oc) * P + pl] = expf((acc[0][j][r] + a.biasBox[oc]) * sc);
        }
      }
    }
  }
}

// ---- GroupNorm pass 2: normalize + affine + ReLU, bf16 -> bf16, coalesced; both towers.
// grid (3424, 2): y = tower
__global__ void gn_norm(const u16* __restrict__ c0, const u16* __restrict__ c1,
                        const float* __restrict__ stats,
                        const float* __restrict__ g0, const float* __restrict__ b0,
                        const float* __restrict__ g1, const float* __restrict__ b1,
                        u16* __restrict__ a0, u16* __restrict__ a1, Tables tb) {
  const int tower = blockIdx.y;
  const u16* convB = tower ? c1 : c0;
  const float* gamma = tower ? g1 : g0;
  const float* beta = tower ? b1 : b0;
  u16* act = tower ? a1 : a0;
  int idx = blockIdx.x * 256 + threadIdx.x;
  int c8 = idx & 31;                 // == group index
  int rest = idx >> 5;
  int p = rest % PA_TOTAL;
  int b = rest / PA_TOTAL;
  int lvl = 0;
#pragma unroll
  for (int i = 1; i < 5; ++i) if (p >= tb.base[i]) lvl = i;
  if (p - tb.base[lvl] >= tb.P[lvl]) return;
  const float* st = stats + tower * 640 + ((size_t)((b * 5 + lvl) * 32 + c8)) * 2;
  float cnt = 8.f * (float)tb.P[lvl];
  float mean = st[0] / cnt;
  float var = st[1] / cnt - mean * mean;
  float inv = rsqrtf(var + 1e-5f);
  const short8 x = *(const short8*)(convB + ((size_t)b * PA_TOTAL + p) * CCH + c8 * 8);
  short8 o;
#pragma unroll
  for (int j = 0; j < 8; ++j) {
    float v = bf2f((u16)x[j]);
    float y = (v - mean) * inv * gamma[c8 * 8 + j] + beta[c8 * 8 + j];
    y = fmaxf(y, 0.f);
    o[j] = (short)f2bf(y);
  }
  *(short8*)(act + ((size_t)b * PA_TOTAL + p) * CCH + c8 * 8) = o;
}

extern "C" void kernel_launch(void* const* d_in, const int* in_sizes, int n_in,
                              void* d_out, int out_size, void* d_ws, size_t ws_size,
                              hipStream_t stream) {
  const float* feat[5];
  for (int i = 0; i < 5; ++i) feat[i] = (const float*)d_in[i];
  const float* cls_tw_w  = (const float*)d_in[5];
  const float* cls_tw_g  = (const float*)d_in[6];
  const float* cls_tw_b  = (const float*)d_in[7];
  const float* box_tw_w  = (const float*)d_in[8];
  const float* box_tw_g  = (const float*)d_in[9];
  const float* box_tw_b  = (const float*)d_in[10];
  const float* cls_pred_w = (const float*)d_in[11];
  const float* cls_pred_b = (const float*)d_in[12];
  const float* box_pred_w = (const float*)d_in[13];
  const float* box_pred_b = (const float*)d_in[14];
  const float* ctr_pred_w = (const float*)d_in[15];
  const float* ctr_pred_b = (const float*)d_in[16];
  const float* scales     = (const float*)d_in[17];
  float* out = (float*)d_out;

  char* ws = (char*)d_ws;
  float* statsAll = (float*)(ws);                    // 4 stages x 1280 floats = 20480 B
  u16*   WrCls  = (u16*)(ws + 24576);                // 1024 x 2304 bf16
  u16*   WrBox  = (u16*)(ws + 24576 + 4718592);
  u16*   WrPCls = (u16*)(ws + 24576 + 2 * 4718592);              // 32 x 2304 (21 used)
  u16*   WrPBox = (u16*)(ws + 24576 + 2 * 4718592 + 147456);     // 32 x 2304 (4 used)
  u16*   bufIn   = (u16*)(ws + 10625024);
  u16*   bufAct0 = (u16*)(ws + 10625024 + 1 * (size_t)14024704);
  u16*   bufAct1 = (u16*)(ws + 10625024 + 2 * (size_t)14024704);
  u16*   bufCv0  = (u16*)(ws + 10625024 + 3 * (size_t)14024704);
  u16*   bufCv1  = (u16*)(ws + 10625024 + 4 * (size_t)14024704);

  Tables tb = { {100,50,25,13,7}, {100,50,25,13,7}, {10000,2500,625,169,49},
                {0,10112,12672,13312,13568}, {0,79,99,104,106},
                {0,400000,500000,525000,531760},
                {533720,613720,633720,638720,640072},
                {640464,660464,665464,666714,667052} };

  // one upfront memset for all 4 stages' stats
  hipMemsetAsync(statsAll, 0, 20480, stream);

  ReorderArgs ra = { cls_tw_w, box_tw_w, cls_pred_w, ctr_pred_w, box_pred_w,
                     WrCls, WrBox, WrPCls, WrPBox };
  reorder_all<<<2112, 256, 0, stream>>>(ra);

  FeatPtrs fp = {{feat[0], feat[1], feat[2], feat[3], feat[4]}};
  convert_inputs<<<dim3(PA_TOTAL / 32, 8, 2), 256, 0, stream>>>(fp, bufIn, tb);

  ConvArgs a;
  a.dout = out;
  a.biasCls = cls_pred_b; a.biasCtr = ctr_pred_b; a.biasBox = box_pred_b; a.scales = scales;
  a.outB[0] = bufCv0; a.outB[1] = bufCv1;

  for (int s = 0; s < 4; ++s) {
    a.X[0] = (s == 0) ? bufIn : bufAct0;
    a.X[1] = (s == 0) ? bufIn : bufAct1;
    a.Wt[0] = WrCls + (size_t)s * 256 * KTOT;
    a.Wt[1] = WrBox + (size_t)s * 256 * KTOT;
    a.stats = statsAll + (size_t)s * 1280;
    conv_mfma<0><<<dim3(107, 2, 4), 256, 0, stream>>>(a, tb);
    gn_norm<<<dim3(3424, 2), 256, 0, stream>>>(bufCv0, bufCv1, a.stats,
                                               cls_tw_g + s * 256, cls_tw_b + s * 256,
                                               box_tw_g + s * 256, box_tw_b + s * 256,
                                               bufAct0, bufAct1, tb);
  }
  a.X[0] = bufAct0; a.X[1] = bufAct1;
  a.Wt[0] = WrPCls; a.Wt[1] = WrPBox;
  conv_mfma<1><<<dim3(108, 2, 2), 256, 0, stream>>>(a, tb);
}